// Round 3
// baseline (969.868 us; speedup 1.0000x reference)
//
#include <hip/hip_runtime.h>

#define N_NODE   10000
#define E_EDGE   320000
#define E_LINKN  1280000
#define DIM      128
#define EFEAT    24
#define SEQLEN   64

#define SCAN_CHUNK 4096   // elements per block in hierarchical scan
#define NB_L 79           // ceil(E_EDGE/SCAN_CHUNK)  (link CSR is over E_EDGE dsts)
#define NB_N 3            // ceil(N_NODE/SCAN_CHUNK)

// ---------------- workspace layout (bytes) ----------------
// zeroed region first (zeroed by consts_kernel): histograms (double as countdown
// cursors in fill) + last-block done counter
static const size_t OFF_DEGN  = 0;                                    // 10240 i32
static const size_t OFF_DEGL  = OFF_DEGN  + 10240*4;                  // E_EDGE i32
static const size_t OFF_DONE  = OFF_DEGL  + (size_t)E_EDGE*4;         // 64 i32 (uses 1)
static const size_t ZERO_BYTES= OFF_DONE  + 256;                      // 1,321,216 (16B-mult)
// non-zeroed:
static const size_t OFF_CONST = ZERO_BYTES;                           // 512 f32 (Ball 432 + cvec 24)
static const size_t OFF_V0    = OFF_CONST + 512*4;                    // [E,6]  f32
static const size_t OFF_V12   = OFF_V0    + (size_t)E_EDGE*6*4;       // [E,16] f32 (12 used, 64B rows)
static const size_t OFF_PW    = OFF_V12   + (size_t)E_EDGE*16*4;      // [E,16] f32 (12 PW + wsum@12)
static const size_t OFF_STARTN= OFF_PW    + (size_t)E_EDGE*16*4;      // 10304 i32 (uses 10001)
static const size_t OFF_SRCSN = OFF_STARTN+ 10304*4;                  // [E] i32 (CSR-sorted src node)
static const size_t OFF_POSN  = OFF_SRCSN + (size_t)E_EDGE*4;         // [E] i32 (edge -> CSR slot)
static const size_t OFF_WKS4  = OFF_POSN  + (size_t)E_EDGE*4;         // [E] float4 (w0,w1,w2,0) CSR-sorted
static const size_t OFF_STARTL= OFF_WKS4  + (size_t)E_EDGE*16;        // E_EDGE+64 i32
static const size_t OFF_LSW   = OFF_STARTL+ ((size_t)E_EDGE+64)*4;    // [E_LINK] int2 (src, w-bits), sorted
static const size_t OFF_HENT  = OFF_LSW   + (size_t)E_LINKN*8;        // [N,128]
static const size_t OFF_HA    = OFF_HENT  + (size_t)N_NODE*DIM*4;     // [N,128]
static const size_t OFF_HB    = OFF_HA    + (size_t)N_NODE*DIM*4;     // [N,128]
static const size_t OFF_HC    = OFF_HB    + (size_t)N_NODE*DIM*4;     // [N,128]
static const size_t OFF_PARTN = OFF_HC    + (size_t)N_NODE*DIM*4;     // 512 i32 (partials+offs, node)
static const size_t OFF_PARTL = OFF_PARTN + 512*4;                    // 512 i32 (partials+offs, link)

// ---------------- consts precompute + workspace zeroing ----------------
// 3 blocks, one per Laguerre term k (identical numerics to verified version).
// Additionally grid-stride zeroes the ZERO_BYTES region (replaces hipMemsetAsync).
__global__ void consts_kernel(const float* __restrict__ Wstart, const float* __restrict__ bstart,
                              const float* __restrict__ Whl,    const float* __restrict__ bhl,
                              const float* __restrict__ Wec,    const float* __restrict__ bec,
                              float* __restrict__ Ball, float* __restrict__ cvec,
                              int4* __restrict__ zreg) {
    __shared__ float M[128*129];   // 66048 B
    __shared__ float sWec[768];
    __shared__ float A[768];       // A[r*6 + j] for this block's k
    int k = blockIdx.x;
    int t = threadIdx.x;

    // zero the histogram/done region (1,321,216 B = 82576 int4)
    for (int i = blockIdx.x*256 + t; i < (int)(ZERO_BYTES/16); i += 3*256)
        zreg[i] = make_int4(0, 0, 0, 0);

    for (int i = t; i < 768; i += 256) sWec[i] = Wec[i];

    const float* w0 = Whl;
    const float* w1 = Whl + 16384;
    const float* w2 = Whl + 32768;
    for (int idx = t; idx < 16384; idx += 256) {
        int r = idx >> 7, d = idx & 127;
        float m;
        if (k == 0)      m = w0[idx] + w1[idx] + w2[idx];
        else if (k == 1) m = -(w1[idx] + 2.f*w2[idx]);
        else             m = 0.5f * w2[idx];
        M[r*129 + d] = m;
    }
    __syncthreads();

    for (int idx = t; idx < 768; idx += 256) {
        int r = idx / 6, j = idx % 6;
        float s = 0.f;
        for (int d = 0; d < 128; d++) s += M[r*129 + d] * sWec[d*6 + j];
        A[idx] = s;
    }
    __syncthreads();

    if (t < 144) {
        int i = t / 6, j = t % 6;
        float s = 0.f;
        for (int r = 0; r < 128; r++) s += Wstart[i*128 + r] * A[r*6 + j];
        Ball[i*18 + k*6 + j] = s;
    } else if (t < 150) {
        int j = t - 144;
        float s = 0.f;
        for (int r = 0; r < 128; r++) s += bstart[r] * A[r*6 + j];
        cvec[k*6 + j] = s;
    } else if (k == 0 && t >= 160 && t < 166) {
        int j = t - 160;
        float s = bec[j];
        for (int d = 0; d < 128; d++) s += bhl[d] * sWec[d*6 + j];
        cvec[18 + j] = s;
    }
}

// ---------------- fused V-compute + both histograms ----------------
// grid = 5000 blocks x 256 (covers E_LINKN exactly). Blocks < 1250 additionally
// do the V compute + node histogram (E_EDGE = 1250*256 exactly, so the guarded
// region is block-uniform and __syncthreads stays legal).
__global__ void v_hist_kernel(const float* __restrict__ x, const float* __restrict__ Ball,
                              const int* __restrict__ dstl, const int* __restrict__ dstn,
                              float* __restrict__ V0, float* __restrict__ V12,
                              int* __restrict__ degl, int* __restrict__ degn) {
    int e = blockIdx.x * 256 + threadIdx.x;
    atomicAdd(degl + dstl[e], 1);            // e < E_LINKN always (exact grid)

    if (blockIdx.x >= 1250) return;          // whole block exits together
    atomicAdd(degn + dstn[e], 1);

    __shared__ float sB[432];
    for (int i = threadIdx.x; i < 432; i += 256) sB[i] = Ball[i];
    __syncthreads();

    float xr[24];
    const float4* xp = (const float4*)(x + (size_t)e*24);
#pragma unroll
    for (int q = 0; q < 6; q++) {
        float4 v = xp[q];
        xr[4*q+0] = v.x; xr[4*q+1] = v.y; xr[4*q+2] = v.z; xr[4*q+3] = v.w;
    }
    float o[18];
#pragma unroll
    for (int j = 0; j < 18; j++) o[j] = 0.f;
#pragma unroll
    for (int i = 0; i < 24; i++) {
        float xv = xr[i];
#pragma unroll
        for (int j = 0; j < 18; j++) o[j] += xv * sB[i*18 + j];
    }
    float2* v0p = (float2*)(V0 + (size_t)e*6);
    v0p[0] = make_float2(o[0], o[1]);
    v0p[1] = make_float2(o[2], o[3]);
    v0p[2] = make_float2(o[4], o[5]);
    float4* v12p = (float4*)(V12 + (size_t)e*16);
    v12p[0] = make_float4(o[6],  o[7],  o[8],  o[9]);
    v12p[1] = make_float4(o[10], o[11], o[12], o[13]);
    v12p[2] = make_float4(o[14], o[15], o[16], o[17]);
}

// ---------------- fused per-block partial sums + (last block) partial scan ----
// grid = NB_L + NB_N = 82 blocks. Last finishing block scans both partial arrays.
__global__ void partial_scanp_kernel(const int* __restrict__ degl, const int* __restrict__ degn,
                                     int* __restrict__ partl, int* __restrict__ partn,
                                     int* __restrict__ done,
                                     int* __restrict__ startl, int* __restrict__ startn) {
    __shared__ int red[256];
    __shared__ int lastflag;
    int b = blockIdx.x, t = threadIdx.x;

    const int* deg; int n, base; int* part;
    if (b < NB_L) { deg = degl; n = E_EDGE;  base = b*SCAN_CHUNK;          part = partl + b; }
    else          { deg = degn; n = N_NODE;  base = (b-NB_L)*SCAN_CHUNK;   part = partn + (b-NB_L); }

    int s = 0;
    for (int i = t; i < SCAN_CHUNK; i += 256) {
        int idx = base + i;
        if (idx < n) s += deg[idx];
    }
    red[t] = s;
    __syncthreads();
    for (int off = 128; off > 0; off >>= 1) {
        if (t < off) red[t] += red[t + off];
        __syncthreads();
    }
    if (t == 0) {
        *part = red[0];
        __threadfence();
        lastflag = (atomicAdd(done, 1) == NB_L + NB_N - 1);
    }
    __syncthreads();
    if (!lastflag) return;
    __threadfence();   // acquire: make all blocks' partial writes visible

    // ---- scan link partials (NB_L entries) ----
    {
        __shared__ int a[256];
        a[t] = (t < NB_L) ? partl[t] : 0;
        __syncthreads();
        for (int off = 1; off < 256; off <<= 1) {
            int v = (t >= off) ? a[t - off] : 0;
            __syncthreads();
            a[t] += v;
            __syncthreads();
        }
        partl[256 + t] = (t == 0) ? 0 : a[t - 1];   // offsL
        if (t == 255) startl[E_EDGE] = a[NB_L - 1];
    }
    __syncthreads();
    // ---- scan node partials (NB_N entries) ----
    {
        __shared__ int a2[256];
        a2[t] = (t < NB_N) ? partn[t] : 0;
        __syncthreads();
        for (int off = 1; off < 256; off <<= 1) {
            int v = (t >= off) ? a2[t - off] : 0;
            __syncthreads();
            a2[t] += v;
            __syncthreads();
        }
        partn[256 + t] = (t == 0) ? 0 : a2[t - 1];  // offsN
        if (t == 255) startn[N_NODE] = a2[NB_N - 1];
    }
}

// ---- per-block exclusive scan + global offset, both arrays, coalesced -------
__global__ void scan_block_kernel(const int* __restrict__ degl, const int* __restrict__ degn,
                                  const int* __restrict__ partl, const int* __restrict__ partn,
                                  int* __restrict__ startl, int* __restrict__ startn) {
    __shared__ int s[SCAN_CHUNK];
    __shared__ int tsum[256];
    int b = blockIdx.x, t = threadIdx.x;

    const int* deg; const int* offs; int* start; int n, base;
    if (b < NB_L) { deg = degl; offs = partl + 256; start = startl; n = E_EDGE; base = b*SCAN_CHUNK; }
    else { deg = degn; offs = partn + 256; start = startn; n = N_NODE; base = (b-NB_L)*SCAN_CHUNK; b -= NB_L; }

    for (int i = t; i < SCAN_CHUNK; i += 256) {
        int idx = base + i;
        s[i] = (idx < n) ? deg[idx] : 0;
    }
    __syncthreads();
    int lo = t * 16;
    int mysum = 0;
#pragma unroll
    for (int j = 0; j < 16; j++) mysum += s[lo + j];
    tsum[t] = mysum;
    __syncthreads();
    for (int off = 1; off < 256; off <<= 1) {
        int v = (t >= off) ? tsum[t - off] : 0;
        __syncthreads();
        tsum[t] += v;
        __syncthreads();
    }
    int run = offs[b] + ((t == 0) ? 0 : tsum[t - 1]);
#pragma unroll
    for (int j = 0; j < 16; j++) {
        int v = s[lo + j];
        s[lo + j] = run;
        run += v;
    }
    __syncthreads();
    for (int i = t; i < SCAN_CHUNK; i += 256) {
        int idx = base + i;
        if (idx < n) start[idx] = s[i];
    }
}

// ---------------- fused CSR fills (deg arrays double as countdown cursors) ----
// grid = 5000 blocks x 256. Link fill always; node fill for blocks < 1250.
__global__ void fill_both_kernel(const int* __restrict__ srcl, const int* __restrict__ dstl,
                                 const float* __restrict__ ewl,
                                 const int* __restrict__ srcn, const int* __restrict__ dstn,
                                 const int* __restrict__ startl, const int* __restrict__ startn,
                                 int* __restrict__ degl, int* __restrict__ degn,
                                 int2* __restrict__ lsw,
                                 int* __restrict__ srcs_srt, int* __restrict__ posn) {
    int e = blockIdx.x * 256 + threadIdx.x;
    {
        int d = dstl[e];
        int old = atomicSub(degl + d, 1);
        int p = startl[d] + old - 1;
        lsw[p] = make_int2(srcl[e], __float_as_int(ewl[e]));
    }
    if (blockIdx.x < 1250) {
        int d = dstn[e];
        int old = atomicSub(degn + d, 1);
        int p = startn[d] + old - 1;
        srcs_srt[p] = srcn[e];
        posn[e] = p;
    }
}

// PW[e,0:12] = sum_links w*V12[src], PW[e,12] = sum w   (pure gather, 1 cacheline/neighbor)
__global__ void prop1_gather(const float* __restrict__ V12, const int* __restrict__ startl,
                             const int2* __restrict__ lsw, float* __restrict__ PW) {
    int e = blockIdx.x * blockDim.x + threadIdx.x;
    if (e >= E_EDGE) return;
    int s0 = startl[e], s1 = startl[e + 1];
    float acc[12];
#pragma unroll
    for (int j = 0; j < 12; j++) acc[j] = 0.f;
    float ws = 0.f;
    int2 cur = make_int2(0, 0);
    if (s0 < s1) cur = lsw[s0];
    for (int j = s0; j < s1; j++) {
        int2 nxt = (j + 1 < s1) ? lsw[j + 1] : cur;
        float w = __int_as_float(cur.y);
        const float4* vp = (const float4*)(V12 + (size_t)cur.x*16);
#pragma unroll
        for (int q = 0; q < 3; q++) {
            float4 v = vp[q];
            acc[4*q+0] += w*v.x; acc[4*q+1] += w*v.y;
            acc[4*q+2] += w*v.z; acc[4*q+3] += w*v.w;
        }
        ws += w;
        cur = nxt;
    }
    float4* pw = (float4*)(PW + (size_t)e*16);
    pw[0] = make_float4(acc[0], acc[1], acc[2],  acc[3]);
    pw[1] = make_float4(acc[4], acc[5], acc[6],  acc[7]);
    pw[2] = make_float4(acc[8], acc[9], acc[10], acc[11]);
    pw[3] = make_float4(ws, 0.f, 0.f, 0.f);
}

// fused: gather P2/wsum2 (one cacheline per neighbor), combine, sigmoid -> wks4 (one 16B store)
__global__ void prop2score_kernel(const float* __restrict__ PW,
                                  const int* __restrict__ startl, const int2* __restrict__ lsw,
                                  const float* __restrict__ V0,
                                  const float* __restrict__ cvec, const int* __restrict__ posn,
                                  float4* __restrict__ wks4) {
    __shared__ float sc[24];
    if (threadIdx.x < 24) sc[threadIdx.x] = cvec[threadIdx.x];
    __syncthreads();
    int e = blockIdx.x * blockDim.x + threadIdx.x;
    if (e >= E_EDGE) return;
    int s0 = startl[e], s1 = startl[e + 1];
    float p2[6];
#pragma unroll
    for (int j = 0; j < 6; j++) p2[j] = 0.f;
    float ws2 = 0.f;
    int2 cur = make_int2(0, 0);
    if (s0 < s1) cur = lsw[s0];
    for (int j = s0; j < s1; j++) {
        int2 nxt = (j + 1 < s1) ? lsw[j + 1] : cur;
        float w = __int_as_float(cur.y);
        const float4* pv = (const float4*)(PW + (size_t)cur.x*16);
        float4 a = pv[1];   // cols 4..7 (use z,w = cols 6,7)
        float4 b = pv[2];   // cols 8..11
        float4 c = pv[3];   // col 12 = wsum in .x
        p2[0] += w*a.z; p2[1] += w*a.w;
        p2[2] += w*b.x; p2[3] += w*b.y; p2[4] += w*b.z; p2[5] += w*b.w;
        ws2 += w * c.x;
        cur = nxt;
    }
    const float4* pe = (const float4*)(PW + (size_t)e*16);
    float4 q0 = pe[0];                 // cols 0..3
    float4 q1 = pe[1];                 // cols 4..7 (use x,y)
    float  ws1 = pe[3].x;              // col 12
    float pw6[6] = {q0.x, q0.y, q0.z, q0.w, q1.x, q1.y};
    const float2* v0p = (const float2*)(V0 + (size_t)e*6);
    float2 f0 = v0p[0], f1 = v0p[1], f2 = v0p[2];
    float v0r[6] = {f0.x, f0.y, f1.x, f1.y, f2.x, f2.y};
    float S[6];
#pragma unroll
    for (int j = 0; j < 6; j++)
        S[j] = v0r[j] + pw6[j] + p2[j]
             + ws1*sc[6 + j] + ws2*sc[12 + j] + sc[j] + sc[18 + j];
    int p = posn[e];
    float w0 = 1.f / (1.f + __expf(S[1] - S[0]));
    float w1 = 1.f / (1.f + __expf(S[3] - S[2]));
    float w2 = 1.f / (1.f + __expf(S[5] - S[4]));
    wks4[p] = make_float4(w0, w1, w2, 0.f);
}

// ---------------- temporal projection ----------------
__global__ void temporal_kernel(const float4* __restrict__ h_entity, const float* __restrict__ Wt,
                                const float* __restrict__ bt, float4* __restrict__ h_ent) {
    __shared__ float sw[SEQLEN];
    if (threadIdx.x < SEQLEN) sw[threadIdx.x] = Wt[threadIdx.x];
    __syncthreads();
    int i = blockIdx.x * blockDim.x + threadIdx.x;            // over N*D/4 = 320000
    if (i >= N_NODE*DIM/4) return;
    float b = bt[0];
    float4 acc = make_float4(b, b, b, b);
#pragma unroll 8
    for (int t = 0; t < SEQLEN; t++) {
        float4 v = h_entity[(size_t)t * (N_NODE*DIM/4) + i];
        float w = sw[t];
        acc.x += w*v.x; acc.y += w*v.y; acc.z += w*v.z; acc.w += w*v.w;
    }
    h_ent[i] = acc;
}

// ---------------- GCN hop propagate: 2 nodes per 256-thr block, (src,w) prefetch
__global__ void prop_hop(const float* __restrict__ h_cur, float* __restrict__ h_next,
                         const int* __restrict__ startn, const int* __restrict__ srcs_srt,
                         const float4* __restrict__ wks4, int k) {
    int half = threadIdx.x >> 7;
    int tid  = threadIdx.x & 127;
    int node = blockIdx.x * 2 + half;            // N_NODE even, grid = N_NODE/2: in range
    int s0 = startn[node], s1 = startn[node + 1];
    float acc = 0.f;
    int sn = 0; float w = 0.f;
    if (s0 < s1) {
        sn = srcs_srt[s0];
        float4 wv = wks4[s0];
        w = (k == 0) ? wv.x : (k == 1) ? wv.y : wv.z;
    }
    for (int j = s0; j < s1; j++) {
        int sn_c = sn; float w_c = w;
        if (j + 1 < s1) {
            sn = srcs_srt[j + 1];
            float4 wv = wks4[j + 1];
            w = (k == 0) ? wv.x : (k == 1) ? wv.y : wv.z;
        }
        acc += w_c * h_cur[(size_t)sn_c*DIM + tid];
    }
    h_next[(size_t)node*DIM + tid] = acc;
}

// ---------------- fused final GEMM: out = b + h1@G1 + h2@G2 + h3@G3
__global__ void __launch_bounds__(256)
gemm_final(const float* __restrict__ h1, const float* __restrict__ h2,
           const float* __restrict__ h3, const float* __restrict__ Wgcn,
           const float* __restrict__ bgcn, float* __restrict__ out) {
    __shared__ float sG[128*128];   // 64 KB
    __shared__ float sh[32*128];    // 16 KB
    int t = threadIdx.x;
    int cg = t & 31, rg = t >> 5;
    int c0 = cg * 4, r0 = rg * 4;
    int rbase = blockIdx.x * 32;
    int nrows = N_NODE - rbase; if (nrows > 32) nrows = 32;

    float4 bb = *(const float4*)(bgcn + c0);
    float acc[4][4];
#pragma unroll
    for (int r = 0; r < 4; r++) {
        acc[r][0] = bb.x; acc[r][1] = bb.y; acc[r][2] = bb.z; acc[r][3] = bb.w;
    }

    const float* hs0[3] = {h1, h2, h3};
    for (int k = 0; k < 3; k++) {
        __syncthreads();
        const float4* gk = (const float4*)(Wgcn + (size_t)k*16384);
        float4* sg4 = (float4*)sG;
        for (int i = t; i < 4096; i += 256) sg4[i] = gk[i];
        const float4* hg = (const float4*)(hs0[k] + (size_t)rbase*128);
        float4* sh4 = (float4*)sh;
        for (int i = t; i < 1024; i += 256)
            sh4[i] = ((i >> 5) < nrows) ? hg[i] : make_float4(0.f, 0.f, 0.f, 0.f);
        __syncthreads();
#pragma unroll 2
        for (int d4 = 0; d4 < 32; d4++) {
            float4 g0 = *(const float4*)(sG + (d4*4 + 0)*128 + c0);
            float4 g1 = *(const float4*)(sG + (d4*4 + 1)*128 + c0);
            float4 g2 = *(const float4*)(sG + (d4*4 + 2)*128 + c0);
            float4 g3 = *(const float4*)(sG + (d4*4 + 3)*128 + c0);
#pragma unroll
            for (int r = 0; r < 4; r++) {
                float4 hv = *(const float4*)(sh + (r0 + r)*128 + d4*4);
                acc[r][0] += hv.x*g0.x; acc[r][1] += hv.x*g0.y; acc[r][2] += hv.x*g0.z; acc[r][3] += hv.x*g0.w;
                acc[r][0] += hv.y*g1.x; acc[r][1] += hv.y*g1.y; acc[r][2] += hv.y*g1.z; acc[r][3] += hv.y*g1.w;
                acc[r][0] += hv.z*g2.x; acc[r][1] += hv.z*g2.y; acc[r][2] += hv.z*g2.z; acc[r][3] += hv.z*g2.w;
                acc[r][0] += hv.w*g3.x; acc[r][1] += hv.w*g3.y; acc[r][2] += hv.w*g3.z; acc[r][3] += hv.w*g3.w;
            }
        }
    }
#pragma unroll
    for (int r = 0; r < 4; r++) {
        if (r0 + r < nrows)
            *(float4*)(out + (size_t)(rbase + r0 + r)*128 + c0) =
                make_float4(acc[r][0], acc[r][1], acc[r][2], acc[r][3]);
    }
}

extern "C" void kernel_launch(void* const* d_in, const int* in_sizes, int n_in,
                              void* d_out, int out_size, void* d_ws, size_t ws_size,
                              hipStream_t stream) {
    const float* h_entity = (const float*)d_in[0];
    const float* x_link   = (const float*)d_in[1];
    const float* ewl      = (const float*)d_in[2];
    const int*   eil      = (const int*)d_in[3];
    const int*   ein      = (const int*)d_in[4];
    const float* Wstart   = (const float*)d_in[5];
    const float* bstart   = (const float*)d_in[6];
    const float* Whl      = (const float*)d_in[7];
    const float* bhl      = (const float*)d_in[8];
    const float* Wec      = (const float*)d_in[9];
    const float* bec      = (const float*)d_in[10];
    const float* Wt       = (const float*)d_in[11];
    const float* bt       = (const float*)d_in[12];
    const float* Wgcn     = (const float*)d_in[13];
    const float* bgcn     = (const float*)d_in[14];
    float* out = (float*)d_out;
    char*  ws  = (char*)d_ws;

    const int* srcl = eil;
    const int* dstl = eil + E_LINKN;
    const int* srcn = ein;
    const int* dstn = ein + E_EDGE;

    int*    degn  = (int*)   (ws + OFF_DEGN);
    int*    degl  = (int*)   (ws + OFF_DEGL);
    int*    done  = (int*)   (ws + OFF_DONE);
    float*  Ball  = (float*) (ws + OFF_CONST);
    float*  cvec  = Ball + 432;
    float*  V0    = (float*) (ws + OFF_V0);
    float*  V12   = (float*) (ws + OFF_V12);
    float*  PW    = (float*) (ws + OFF_PW);
    int*    startn= (int*)   (ws + OFF_STARTN);
    int*    srcsn = (int*)   (ws + OFF_SRCSN);
    int*    posn  = (int*)   (ws + OFF_POSN);
    float4* wks4  = (float4*)(ws + OFF_WKS4);
    int*    startl= (int*)   (ws + OFF_STARTL);
    int2*   lsw   = (int2*)  (ws + OFF_LSW);
    float*  h_ent = (float*) (ws + OFF_HENT);
    float*  h_a   = (float*) (ws + OFF_HA);
    float*  h_b   = (float*) (ws + OFF_HB);
    float*  h_c   = (float*) (ws + OFF_HC);
    int*    partn = (int*)   (ws + OFF_PARTN);  // partials, offs = partn+256
    int*    partl = (int*)   (ws + OFF_PARTL);

    // 1. consts + workspace zeroing
    consts_kernel<<<3, 256, 0, stream>>>(Wstart, bstart, Whl, bhl, Wec, bec,
                                         Ball, cvec, (int4*)ws);
    // 2. V compute + both histograms
    v_hist_kernel<<<E_LINKN/256, 256, 0, stream>>>(x_link, Ball, dstl, dstn,
                                                   V0, V12, degl, degn);
    // 3. per-block partials + last-block scan of partials (both graphs)
    partial_scanp_kernel<<<NB_L + NB_N, 256, 0, stream>>>(degl, degn, partl, partn,
                                                          done, startl, startn);
    // 4. per-chunk exclusive scans (both graphs)
    scan_block_kernel<<<NB_L + NB_N, 256, 0, stream>>>(degl, degn, partl, partn,
                                                       startl, startn);
    // 5. both CSR fills (deg arrays as countdown cursors)
    fill_both_kernel<<<E_LINKN/256, 256, 0, stream>>>(srcl, dstl, ewl, srcn, dstn,
                                                      startl, startn, degl, degn,
                                                      lsw, srcsn, posn);
    // 6-7. link-graph propagates (gather)
    prop1_gather<<<(E_EDGE + 255)/256, 256, 0, stream>>>(V12, startl, lsw, PW);
    prop2score_kernel<<<(E_EDGE + 255)/256, 256, 0, stream>>>(PW, startl, lsw, V0, cvec,
                                                              posn, wks4);
    // 8. temporal projection
    temporal_kernel<<<(N_NODE*DIM/4 + 255)/256, 256, 0, stream>>>(
        (const float4*)h_entity, Wt, bt, (float4*)h_ent);
    // 9-11. GCN hops (2 nodes per block)
    prop_hop<<<N_NODE/2, 256, 0, stream>>>(h_ent, h_a, startn, srcsn, wks4, 0);
    prop_hop<<<N_NODE/2, 256, 0, stream>>>(h_a,   h_b, startn, srcsn, wks4, 1);
    prop_hop<<<N_NODE/2, 256, 0, stream>>>(h_b,   h_c, startn, srcsn, wks4, 2);
    // 12. fused final GEMM
    gemm_final<<<(N_NODE + 31)/32, 256, 0, stream>>>(h_a, h_b, h_c, Wgcn, bgcn, out);
}